// Round 5
// baseline (3136.042 us; speedup 1.0000x reference)
//
#include <hip/hip_runtime.h>
#include <math.h>

namespace {

constexpr int B = 8, T = 10, C = 32, H = 128, W = 128;
constexpr int HW = H * W;            // 16384
constexpr int CHW = C * HW;          // 524288
constexpr int BHW = B * HW;
constexpr int NBLK = 1024;           // 8 b x 16 th x 8 tw  == 4 blocks/CU x 256 CU

constexpr float DF = 0.90483741803595952f;  // exp(-0.1)
constexpr float DL = 0.36787944117144233f;  // exp(-1.0)
constexpr float DE = 0.36787944117144233f;  // exp(-1.0)
constexpr float VE = 10.0f;

// wgt[co][ci][kh][kw] -> wtr[ci][k][co]; also zero the grid-barrier counter.
__global__ void k_wtr(const float* __restrict__ wgt, float* __restrict__ wtr,
                      unsigned* __restrict__ bar) {
  int i = blockIdx.x * 256 + threadIdx.x;
  if (i == 0) bar[0] = 0u;
  if (i >= C * C * 9) return;
  int ci = i / 288;
  int k = (i / 32) % 9;
  int co = i & 31;
  wtr[i] = wgt[co * 288 + ci * 9 + k];
}

// Persistent fused kernel: all T steps, f/l/e in registers, grid barrier
// between steps. Grid MUST be exactly NBLK=1024 (co-resident: 256 thr,
// <=128 VGPR, 39.4 KB LDS -> 4 blocks/CU x 256 CU).
__launch_bounds__(256, 4)
__global__ void k_fused(const float* __restrict__ x, const float* __restrict__ wtr,
                        const float* __restrict__ bias, float* __restrict__ sA,
                        float* __restrict__ sB, float* __restrict__ out,
                        unsigned* __restrict__ bar) {
  __shared__ float ysl[2][8][10][25];  // [buf][ci][row][slot]  slot = w-(w0-4)
  __shared__ float wsl[2][8][9][32];   // [buf][ci][k][c_out]
  __shared__ float sl[10][21];         // channel-sum tile (+halo)
  __shared__ float sred[8][32][4];     // chansum partials

  const int tid = threadIdx.x;
  const int bid = blockIdx.x;
  const int tw = bid & 7, th = (bid >> 3) & 15, b = bid >> 7;
  const int h0 = th * 8, w0 = tw * 16;
  const int g = tid >> 5, s = tid & 31;
  const int sh = s >> 2, sw = s & 3;
  const int cb = 4 * sw;
  const int gh = h0 + sh, gwc = w0 + cb;

  // persistent per-thread state: 4 c_out x 4 px
  float fS[4][4], lS[4][4], eS[4][4];
#pragma unroll
  for (int q = 0; q < 4; ++q)
#pragma unroll
    for (int p = 0; p < 4; ++p) {
      fS[q][p] = 0.f;
      lS[q][p] = 0.f;
      eS[q][p] = 10.f;  // V_E / ALPHA_E
    }
  const float4 bc4 = *(const float4*)&bias[4 * g];
  const float bc[4] = {bc4.x, bc4.y, bc4.z, bc4.w};

  for (int t = 0; t < T; ++t) {
    float acc[4][4] = {};
    float linc[4] = {0.f, 0.f, 0.f, 0.f};

    if (t > 0) {
      const float* ybase = out + ((size_t)b * T + (t - 1)) * CHW;
      const float* s_in = ((t - 1) & 1) ? sB : sA;

      auto stage = [&](int cc, int nb) {
        const float4* wsrc = (const float4*)(wtr + cc * 2304);
        float4* wdst = (float4*)&wsl[nb][0][0][0];
        for (int i = tid; i < 576; i += 256) wdst[i] = wsrc[i];
        for (int idx = tid; idx < 480; idx += 256) {
          int cil = idx / 60;
          int rem = idx % 60;
          int rr = rem / 6;
          int j = rem % 6;
          int gh2 = h0 - 1 + rr;
          int ws2 = w0 - 4 + 4 * j;
          float4 v = make_float4(0.f, 0.f, 0.f, 0.f);
          if ((unsigned)gh2 < (unsigned)H && (unsigned)ws2 <= (unsigned)(W - 4))
            v = *(const float4*)(ybase + (size_t)(cc * 8 + cil) * HW + gh2 * W + ws2);
          float* dst = &ysl[nb][cil][rr][4 * j];
          dst[0] = v.x;
          dst[1] = v.y;
          dst[2] = v.z;
          dst[3] = v.w;
        }
      };

      for (int i = tid; i < 180; i += 256) {
        int rr = i / 18, cl = i % 18;
        int gh2 = h0 - 1 + rr, gw2 = w0 - 1 + cl;
        float v = 0.f;
        if ((unsigned)gh2 < (unsigned)H && (unsigned)gw2 < (unsigned)W)
          v = s_in[(size_t)b * HW + gh2 * W + gw2];
        sl[rr][cl] = v;
      }
      stage(0, 0);
      __syncthreads();

#pragma unroll
      for (int p = 0; p < 4; ++p) {
        const int c0 = cb + p;
        linc[p] = 0.5f * (sl[sh][c0] + sl[sh][c0 + 2] + sl[sh + 2][c0] +
                          sl[sh + 2][c0 + 2]) +
                  sl[sh][c0 + 1] + sl[sh + 2][c0 + 1] + sl[sh + 1][c0] +
                  sl[sh + 1][c0 + 2];
      }

#pragma unroll 1
      for (int cc = 0; cc < 4; ++cc) {
        const int nb = cc & 1;
        if (cc < 3) stage(cc + 1, nb ^ 1);
#pragma unroll
        for (int cil = 0; cil < 8; ++cil) {
          float yv[3][6];
#pragma unroll
          for (int dh = 0; dh < 3; ++dh)
#pragma unroll
            for (int dx = 0; dx < 6; ++dx)
              yv[dh][dx] = ysl[nb][cil][sh + dh][cb + 3 + dx];
#pragma unroll
          for (int k = 0; k < 9; ++k) {
            const int kh = k / 3, kw = k % 3;
            float4 wk = *(const float4*)&wsl[nb][cil][k][4 * g];
            float wq[4] = {wk.x, wk.y, wk.z, wk.w};
#pragma unroll
            for (int q = 0; q < 4; ++q)
#pragma unroll
              for (int p = 0; p < 4; ++p)
                acc[q][p] = fmaf(wq[q], yv[kh][p + kw], acc[q][p]);
          }
        }
        __syncthreads();
      }
    }

    // epilogue: state update in registers, write y to out[t]
    float sp[4] = {0.f, 0.f, 0.f, 0.f};
#pragma unroll
    for (int q = 0; q < 4; ++q) {
      const int c = 4 * g + q;
      const size_t oidx =
          (((size_t)b * T + t) * C + c) * (size_t)HW + (size_t)gh * W + gwc;
      float4 x4 = *(const float4*)(x + oidx);
      float4 yo4 = make_float4(0.f, 0.f, 0.f, 0.f);
      if (t > 0) yo4 = *(const float4*)(out + oidx - CHW);
      float xr[4] = {x4.x, x4.y, x4.z, x4.w};
      float yr[4] = {yo4.x, yo4.y, yo4.z, yo4.w};
      float yn[4];
#pragma unroll
      for (int p = 0; p < 4; ++p) {
        float fn = DF * fS[q][p] + acc[q][p] + bc[q] + xr[p];
        float ln = DL * lS[q][p] + linc[p];
        float u = fmaf(0.5f * fn, ln, fn);
        float en = DE * eS[q][p] + VE * yr[p];
        float yy = 1.f / (1.f + __expf(en - u));
        fS[q][p] = fn;
        lS[q][p] = ln;
        eS[q][p] = en;
        yn[p] = yy;
        sp[p] += yy;
      }
      *(float4*)(out + oidx) = make_float4(yn[0], yn[1], yn[2], yn[3]);
    }

    if (t < T - 1) {
      // fused channel-sum for next step
      *(float4*)&sred[g][s][0] = make_float4(sp[0], sp[1], sp[2], sp[3]);
      __syncthreads();
      if (tid < 32) {
        float4 a = *(const float4*)&sred[0][tid][0];
#pragma unroll
        for (int gg = 1; gg < 8; ++gg) {
          float4 bq = *(const float4*)&sred[gg][tid][0];
          a.x += bq.x;
          a.y += bq.y;
          a.z += bq.z;
          a.w += bq.w;
        }
        float* s_out = (t & 1) ? sB : sA;
        const int rh = tid >> 2, rw = 4 * (tid & 3);
        *(float4*)(s_out + (size_t)b * HW + (size_t)(h0 + rh) * W + w0 + rw) = a;
      }
      __syncthreads();  // all waves drain their stores (vmcnt(0) before barrier)

      // grid-wide barrier, monotonic counter (no reset -> no race)
      if (tid == 0) {
        __threadfence();  // release: writeback L2 (cross-XCD visibility)
        unsigned arr = __hip_atomic_fetch_add(bar, 1u, __ATOMIC_ACQ_REL,
                                              __HIP_MEMORY_SCOPE_AGENT);
        unsigned target = ((arr / NBLK) + 1u) * NBLK;
        while (__hip_atomic_load(bar, __ATOMIC_ACQUIRE,
                                 __HIP_MEMORY_SCOPE_AGENT) < target)
          __builtin_amdgcn_s_sleep(16);
        __threadfence();  // acquire: invalidate stale L1/L2
      }
      __syncthreads();
    }
  }
}

}  // namespace

extern "C" void kernel_launch(void* const* d_in, const int* in_sizes, int n_in,
                              void* d_out, int out_size, void* d_ws, size_t ws_size,
                              hipStream_t stream) {
  (void)in_sizes; (void)n_in; (void)out_size; (void)ws_size;
  const float* x = (const float*)d_in[0];     // (B,T,C,H,W)
  const float* wgt = (const float*)d_in[1];   // (C,C,3,3)
  const float* bias = (const float*)d_in[2];  // (C,)
  float* out = (float*)d_out;                 // (B,T,C,H,W)

  float* ws = (float*)d_ws;
  float* wtr = ws;                  // 9216 floats
  float* sA = wtr + 9216;           // BHW
  float* sB = sA + BHW;             // BHW
  unsigned* bar = (unsigned*)(sB + BHW);

  k_wtr<<<36, 256, 0, stream>>>(wgt, wtr, bar);
  k_fused<<<NBLK, 256, 0, stream>>>(x, wtr, bias, sA, sB, out, bar);
}

// Round 7
// 2882.094 us; speedup vs baseline: 1.0881x; 1.0881x over previous
//
#include <hip/hip_runtime.h>
#include <math.h>

namespace {

constexpr int B = 8, T = 10, C = 32, H = 128, W = 128;
constexpr int HW = H * W;            // 16384
constexpr int CHW = C * HW;          // 524288
constexpr int BHW = B * HW;
constexpr int NBLK = 1024;           // 8 b x 16 th x 8 tw == 4 blocks/CU x 256 CU

constexpr float DF = 0.90483741803595952f;  // exp(-0.1)
constexpr float DL = 0.36787944117144233f;  // exp(-1.0)
constexpr float DE = 0.36787944117144233f;  // exp(-1.0)
constexpr float VE = 10.0f;

// wgt[co][ci][kh][kw] -> wtr[ci][k][co]; also zero the grid-barrier counter.
__global__ void k_wtr(const float* __restrict__ wgt, float* __restrict__ wtr,
                      unsigned* __restrict__ bar) {
  int i = blockIdx.x * 256 + threadIdx.x;
  if (i == 0) bar[0] = 0u;
  if (i >= C * C * 9) return;
  int ci = i / 288;
  int k = (i / 32) % 9;
  int co = i & 31;
  wtr[i] = wgt[co * 288 + ci * 9 + k];
}

// Persistent fused kernel: all T steps, f/e (per c_out x px) and l (channel-
// uniform!) in registers, grid barrier between steps.
// e-fold: reference uses e_new = DE*e + VE*y_old BEFORE the sigmoid, so the
// folded recurrence  yy = sigmoid(u - eS); eS = DE*eS + VE*yy  is exact iff
// eS is initialized to e_used(0) = DE * (V_E/ALPHA_E) = DE*10.  (R6 bug:
// initialized to 10 -> absmax 1.0.)
// VGPR discipline: waves_per_eu(4,4) -> allocator budget exactly 128 (512-reg
// SIMD file / 4 waves). min=4 also ENFORCES V<=128, so 4 blocks/CU (LDS
// 39.4KB x 4 = 157.3KB) co-residency is guaranteed -> barrier cannot deadlock.
__attribute__((amdgpu_flat_work_group_size(256, 256), amdgpu_waves_per_eu(4, 4)))
__global__ void k_fused(const float* __restrict__ x, const float* __restrict__ wtr,
                        const float* __restrict__ bias, float* __restrict__ sA,
                        float* __restrict__ sB, float* __restrict__ out,
                        unsigned* __restrict__ bar) {
  __shared__ float ysl[2][8][10][25];  // [buf][ci][row][slot]  slot = w-(w0-4)
  __shared__ float wsl[2][8][9][32];   // [buf][ci][k][c_out]
  __shared__ float sl[10][21];         // channel-sum tile (+halo)
  __shared__ float sred[8][32][4];     // chansum partials

  const int tid = threadIdx.x;
  const int bid = blockIdx.x;
  const int tw = bid & 7, th = (bid >> 3) & 15, b = bid >> 7;
  const int h0 = th * 8, w0 = tw * 16;
  const int g = tid >> 5, s = tid & 31;
  const int sh = s >> 2, sw = s & 3;
  const int cb = 4 * sw;
  const int gh = h0 + sh, gwc = w0 + cb;

  // persistent per-thread state
  float fS[4][4];   // f: 4 c_out x 4 px
  float eS[4][4];   // e-entry: holds e_used(t) at entry of step t
  float lS[4];      // l: channel-uniform -> per px only
#pragma unroll
  for (int p = 0; p < 4; ++p) lS[p] = 0.f;
#pragma unroll
  for (int q = 0; q < 4; ++q)
#pragma unroll
    for (int p = 0; p < 4; ++p) {
      fS[q][p] = 0.f;
      eS[q][p] = 3.6787944117144233f;  // DE * (V_E/ALPHA_E) -- see e-fold note
    }
  const float4 bc4 = *(const float4*)&bias[4 * g];
  const float bc[4] = {bc4.x, bc4.y, bc4.z, bc4.w};

  for (int t = 0; t < T; ++t) {
    float acc[4][4] = {};
    float linc[4] = {0.f, 0.f, 0.f, 0.f};

    if (t > 0) {
      const float* ybase = out + ((size_t)b * T + (t - 1)) * CHW;
      const float* s_in = ((t - 1) & 1) ? sB : sA;

      auto stage = [&](int cc, int nb) {
        const float4* wsrc = (const float4*)(wtr + cc * 2304);
        float4* wdst = (float4*)&wsl[nb][0][0][0];
        for (int i = tid; i < 576; i += 256) wdst[i] = wsrc[i];
        for (int idx = tid; idx < 480; idx += 256) {
          int cil = idx / 60;
          int rem = idx % 60;
          int rr = rem / 6;
          int j = rem % 6;
          int gh2 = h0 - 1 + rr;
          int ws2 = w0 - 4 + 4 * j;
          float4 v = make_float4(0.f, 0.f, 0.f, 0.f);
          if ((unsigned)gh2 < (unsigned)H && (unsigned)ws2 <= (unsigned)(W - 4))
            v = *(const float4*)(ybase + (size_t)(cc * 8 + cil) * HW + gh2 * W + ws2);
          float* dst = &ysl[nb][cil][rr][4 * j];
          dst[0] = v.x;
          dst[1] = v.y;
          dst[2] = v.z;
          dst[3] = v.w;
        }
      };

      for (int i = tid; i < 180; i += 256) {
        int rr = i / 18, cl = i % 18;
        int gh2 = h0 - 1 + rr, gw2 = w0 - 1 + cl;
        float v = 0.f;
        if ((unsigned)gh2 < (unsigned)H && (unsigned)gw2 < (unsigned)W)
          v = s_in[(size_t)b * HW + gh2 * W + gw2];
        sl[rr][cl] = v;
      }
      stage(0, 0);
      __syncthreads();

#pragma unroll
      for (int p = 0; p < 4; ++p) {
        const int c0 = cb + p;
        linc[p] = 0.5f * (sl[sh][c0] + sl[sh][c0 + 2] + sl[sh + 2][c0] +
                          sl[sh + 2][c0 + 2]) +
                  sl[sh][c0 + 1] + sl[sh + 2][c0 + 1] + sl[sh + 1][c0] +
                  sl[sh + 1][c0 + 2];
      }

#pragma unroll 1
      for (int cc = 0; cc < 4; ++cc) {
        const int nb = cc & 1;
        if (cc < 3) stage(cc + 1, nb ^ 1);
#pragma unroll
        for (int cil = 0; cil < 8; ++cil) {
          float yv[3][6];
#pragma unroll
          for (int dh = 0; dh < 3; ++dh)
#pragma unroll
            for (int dx = 0; dx < 6; ++dx)
              yv[dh][dx] = ysl[nb][cil][sh + dh][cb + 3 + dx];
#pragma unroll
          for (int k = 0; k < 9; ++k) {
            const int kh = k / 3, kw = k % 3;
            float4 wk = *(const float4*)&wsl[nb][cil][k][4 * g];
            float wq[4] = {wk.x, wk.y, wk.z, wk.w};
#pragma unroll
            for (int q = 0; q < 4; ++q)
#pragma unroll
              for (int p = 0; p < 4; ++p)
                acc[q][p] = fmaf(wq[q], yv[kh][p + kw], acc[q][p]);
          }
        }
        __syncthreads();
      }
    }

    // epilogue: state update fully in registers, write y to out[t]
    // l first (channel-uniform, once per px)
#pragma unroll
    for (int p = 0; p < 4; ++p) lS[p] = DL * lS[p] + linc[p];

    float sp[4] = {0.f, 0.f, 0.f, 0.f};
#pragma unroll
    for (int q = 0; q < 4; ++q) {
      const int c = 4 * g + q;
      const size_t oidx =
          (((size_t)b * T + t) * C + c) * (size_t)HW + (size_t)gh * W + gwc;
      float4 x4 = *(const float4*)(x + oidx);
      float xr[4] = {x4.x, x4.y, x4.z, x4.w};
      float yn[4];
#pragma unroll
      for (int p = 0; p < 4; ++p) {
        float fn = DF * fS[q][p] + acc[q][p] + bc[q] + xr[p];
        float u = fmaf(0.5f * fn, lS[p], fn);
        float yy = 1.f / (1.f + __expf(eS[q][p] - u));
        fS[q][p] = fn;
        eS[q][p] = DE * eS[q][p] + VE * yy;  // = e_used(t+1)
        yn[p] = yy;
        sp[p] += yy;
      }
      *(float4*)(out + oidx) = make_float4(yn[0], yn[1], yn[2], yn[3]);
    }

    if (t < T - 1) {
      // fused channel-sum for next step's fixed conv
      *(float4*)&sred[g][s][0] = make_float4(sp[0], sp[1], sp[2], sp[3]);
      __syncthreads();
      if (tid < 32) {
        float4 a = *(const float4*)&sred[0][tid][0];
#pragma unroll
        for (int gg = 1; gg < 8; ++gg) {
          float4 bq = *(const float4*)&sred[gg][tid][0];
          a.x += bq.x;
          a.y += bq.y;
          a.z += bq.z;
          a.w += bq.w;
        }
        float* s_out = (t & 1) ? sB : sA;
        const int rh = tid >> 2, rw = 4 * (tid & 3);
        *(float4*)(s_out + (size_t)b * HW + (size_t)(h0 + rh) * W + w0 + rw) = a;
      }
      __syncthreads();  // all stores issued before the grid barrier

      // grid-wide barrier, monotonic counter (R5-proven correct)
      if (tid == 0) {
        __threadfence();  // release: make out/s visible device-wide
        unsigned arr = __hip_atomic_fetch_add(bar, 1u, __ATOMIC_ACQ_REL,
                                              __HIP_MEMORY_SCOPE_AGENT);
        unsigned target = ((arr / NBLK) + 1u) * NBLK;
        while (__hip_atomic_load(bar, __ATOMIC_ACQUIRE,
                                 __HIP_MEMORY_SCOPE_AGENT) < target)
          __builtin_amdgcn_s_sleep(16);
        __threadfence();  // acquire: drop stale L1/L2 lines
      }
      __syncthreads();
    }
  }
}

}  // namespace

extern "C" void kernel_launch(void* const* d_in, const int* in_sizes, int n_in,
                              void* d_out, int out_size, void* d_ws, size_t ws_size,
                              hipStream_t stream) {
  (void)in_sizes; (void)n_in; (void)out_size; (void)ws_size;
  const float* x = (const float*)d_in[0];     // (B,T,C,H,W)
  const float* wgt = (const float*)d_in[1];   // (C,C,3,3)
  const float* bias = (const float*)d_in[2];  // (C,)
  float* out = (float*)d_out;                 // (B,T,C,H,W)

  float* ws = (float*)d_ws;
  float* wtr = ws;                  // 9216 floats
  float* sA = wtr + 9216;           // BHW
  float* sB = sA + BHW;             // BHW
  unsigned* bar = (unsigned*)(sB + BHW);

  k_wtr<<<36, 256, 0, stream>>>(wgt, wtr, bar);
  k_fused<<<NBLK, 256, 0, stream>>>(x, wtr, bias, sA, sB, out, bar);
}

// Round 9
// 609.453 us; speedup vs baseline: 5.1457x; 4.7290x over previous
//
#include <hip/hip_runtime.h>
#include <math.h>

namespace {

constexpr int B = 8, T = 10, C = 32, H = 128, W = 128;
constexpr int HW = H * W;            // 16384
constexpr int CHW = C * HW;          // 524288
constexpr int BHW = B * HW;
constexpr long long NSTATE = (long long)B * CHW;

constexpr float DF = 0.90483741803595952f;  // exp(-0.1)
constexpr float DL = 0.36787944117144233f;  // exp(-1.0)
constexpr float DE = 0.36787944117144233f;  // exp(-1.0)
constexpr float VE = 10.0f;
constexpr float E0 = 3.6787944117144233f;   // DE * (V_E/ALPHA_E), e-fold init

// wgt[co][ci][kh][kw] -> wtr[ci][k][co]   (9216 floats)
__global__ void k_wtr(const float* __restrict__ wgt, float* __restrict__ wtr) {
  int i = blockIdx.x * 256 + threadIdx.x;
  if (i >= C * C * 9) return;
  int ci = i / 288;
  int k = (i / 32) % 9;
  int co = i & 31;
  wtr[i] = wgt[co * 288 + ci * 9 + k];
}

// t=0: y_prev=0 -> conv=0, l=0, u=f. Writes f, e_used(1), out[0], s, l-plane.
__launch_bounds__(256, 2)
__global__ void k_step0(const float* __restrict__ x, const float* __restrict__ bias,
                        float* __restrict__ f, float* __restrict__ e,
                        float* __restrict__ lpl, float* __restrict__ out,
                        float* __restrict__ s_out) {
  __shared__ float sred[8][32][4];
  const int tid = threadIdx.x, bid = blockIdx.x;
  const int tw = bid & 7, th = (bid >> 3) & 15, b = bid >> 7;
  const int h0 = th * 8, w0 = tw * 16;
  const int g = tid >> 5, s = tid & 31;
  const int sh = s >> 2, sw = s & 3, cb = 4 * sw;
  const int gh = h0 + sh, gwc = w0 + cb;
  const float4 bc4 = *(const float4*)&bias[4 * g];
  const float bc[4] = {bc4.x, bc4.y, bc4.z, bc4.w};

  float sp[4] = {0.f, 0.f, 0.f, 0.f};
#pragma unroll
  for (int q = 0; q < 4; ++q) {
    const int c = 4 * g + q;
    const size_t sidx = (size_t)b * CHW + (size_t)c * HW + (size_t)gh * W + gwc;
    const size_t oidx = (((size_t)b * T) * C + c) * (size_t)HW + (size_t)gh * W + gwc;
    float4 x4 = *(const float4*)(x + oidx);
    float xr[4] = {x4.x, x4.y, x4.z, x4.w};
    float fo[4], eo[4], yn[4];
#pragma unroll
    for (int p = 0; p < 4; ++p) {
      float fn = bc[q] + xr[p];              // DF*0 + conv(0) + bias + x
      float yy = 1.f / (1.f + __expf(E0 - fn));  // u = fn*(1+0.5*0) = fn
      fo[p] = fn;
      eo[p] = DE * E0 + VE * yy;             // e_used(1)
      yn[p] = yy;
      sp[p] += yy;
    }
    *(float4*)(f + sidx) = make_float4(fo[0], fo[1], fo[2], fo[3]);
    *(float4*)(e + sidx) = make_float4(eo[0], eo[1], eo[2], eo[3]);
    *(float4*)(out + oidx) = make_float4(yn[0], yn[1], yn[2], yn[3]);
  }
  *(float4*)&sred[g][s][0] = make_float4(sp[0], sp[1], sp[2], sp[3]);
  __syncthreads();
  if (tid < 32) {
    float4 a = *(const float4*)&sred[0][tid][0];
#pragma unroll
    for (int gg = 1; gg < 8; ++gg) {
      float4 bq = *(const float4*)&sred[gg][tid][0];
      a.x += bq.x; a.y += bq.y; a.z += bq.z; a.w += bq.w;
    }
    const size_t pidx = (size_t)b * HW + (size_t)gh * W + gwc;  // g==0: own px
    *(float4*)(s_out + pidx) = a;
    *(float4*)(lpl + pidx) = make_float4(0.f, 0.f, 0.f, 0.f);   // l_1 = 0
  }
}

// Steps 1..T-1. 1024 blocks x 256 threads, tile 8 rows x 16 cols, 32 c_out.
// Thread: g=tid>>5 owns c_out 4g..4g+3; s=tid&31 -> (sh,sw) 4-px strip.
// ci in 4 chunks of 8, SINGLE LDS buffer + register prefetch (T14 split):
// chunk cc+1's global loads are issued before chunk cc's FMAs, LDS-committed
// after the barrier. Deadlock-immune (no grid barrier).
__launch_bounds__(256, 2)
__global__ void k_step(const float* __restrict__ x, const float* __restrict__ wtr,
                       const float* __restrict__ bias, const float* __restrict__ s_in,
                       float* __restrict__ s_out, float* __restrict__ f,
                       float* __restrict__ e, float* __restrict__ lpl,
                       float* __restrict__ out, int t) {
  __shared__ float ysl[8][10][28];   // stride 28 -> rows 16B-aligned, bank-spread
  __shared__ float wsl[8][9][32];    // [ci][k][c_out]
  __shared__ float sl[10][21];       // channel-sum tile (+halo)
  __shared__ float sred[8][32][4];   // chansum partials

  const int tid = threadIdx.x, bid = blockIdx.x;
  const int tw = bid & 7, th = (bid >> 3) & 15, b = bid >> 7;
  const int h0 = th * 8, w0 = tw * 16;
  const int g = tid >> 5, s = tid & 31;
  const int sh = s >> 2, sw = s & 3, cb = 4 * sw;
  const int gh = h0 + sh, gwc = w0 + cb;

  const float* ybase = out + ((size_t)b * T + (t - 1)) * CHW;

  // stage channel-sum tile (visible after first barrier)
  for (int i = tid; i < 180; i += 256) {
    int rr = i / 18, cl = i % 18;
    int gh2 = h0 - 1 + rr, gw2 = w0 - 1 + cl;
    float v = 0.f;
    if ((unsigned)gh2 < (unsigned)H && (unsigned)gw2 < (unsigned)W)
      v = s_in[(size_t)b * HW + gh2 * W + gw2];
    sl[rr][cl] = v;
  }

  // l-plane read (channel-uniform); becomes l_new once linc is known
  float4 l4 = *(const float4*)(lpl + (size_t)b * HW + (size_t)gh * W + gwc);
  float lnew[4] = {l4.x, l4.y, l4.z, l4.w};

  // y-prefetch slots (chunk-invariant address parts). 480 float4 per chunk.
  const int i0 = tid;                                  // slot 0: always valid
  const int cil0 = i0 / 60, rr0 = (i0 % 60) / 6, j0 = i0 % 6;
  const int gh0p = h0 - 1 + rr0, ws0p = w0 - 4 + 4 * j0;
  const bool ok0 = (unsigned)gh0p < (unsigned)H && (unsigned)ws0p <= (unsigned)(W - 4);
  const size_t yoff0 = (size_t)cil0 * HW + (size_t)(ok0 ? gh0p * W + ws0p : 0);
  float* const yd0 = &ysl[cil0][rr0][4 * j0];
  const int i1 = tid + 256;                            // slot 1: valid if <480
  const bool use1 = i1 < 480;
  const int cil1 = (i1 / 60) & 7, rr1 = (i1 % 60) / 6, j1 = i1 % 6;
  const int gh1p = h0 - 1 + rr1, ws1p = w0 - 4 + 4 * j1;
  const bool ok1 = use1 && (unsigned)gh1p < (unsigned)H &&
                   (unsigned)ws1p <= (unsigned)(W - 4);
  const size_t yoff1 = (size_t)cil1 * HW + (size_t)(ok1 ? gh1p * W + ws1p : 0);
  float* const yd1 = &ysl[cil1][rr1][4 * j1];

  const float4* const wsrc = (const float4*)wtr;       // 576 float4 per chunk
  float4* const wlds = (float4*)&wsl[0][0][0];

  float4 y0v, y1v, w0v, w1v, w2v;
  auto prefetch = [&](int cc) {
    const float* yb = ybase + (size_t)cc * 8 * HW;
    y0v = ok0 ? *(const float4*)(yb + yoff0) : make_float4(0.f, 0.f, 0.f, 0.f);
    y1v = ok1 ? *(const float4*)(yb + yoff1) : make_float4(0.f, 0.f, 0.f, 0.f);
    const float4* wb = wsrc + cc * 576;
    w0v = wb[tid];
    w1v = wb[tid + 256];
    w2v = (tid < 64) ? wb[tid + 512] : make_float4(0.f, 0.f, 0.f, 0.f);
  };
  prefetch(0);

  float acc[4][4] = {};

#pragma unroll 1
  for (int cc = 0; cc < 4; ++cc) {
    __syncthreads();  // previous chunk's LDS reads complete
    // commit prefetched chunk to LDS (scalar y stores: stride-28 rows, 4j offset)
    yd0[0] = y0v.x; yd0[1] = y0v.y; yd0[2] = y0v.z; yd0[3] = y0v.w;
    if (use1) { yd1[0] = y1v.x; yd1[1] = y1v.y; yd1[2] = y1v.z; yd1[3] = y1v.w; }
    wlds[tid] = w0v;
    wlds[tid + 256] = w1v;
    if (tid < 64) wlds[tid + 512] = w2v;
    __syncthreads();  // LDS visible
    if (cc < 3) prefetch(cc + 1);  // loads in flight under this chunk's FMAs
    if (cc == 0) {
      float linc[4];
#pragma unroll
      for (int p = 0; p < 4; ++p) {
        const int c0 = cb + p;
        linc[p] = 0.5f * (sl[sh][c0] + sl[sh][c0 + 2] + sl[sh + 2][c0] +
                          sl[sh + 2][c0 + 2]) +
                  sl[sh][c0 + 1] + sl[sh + 2][c0 + 1] + sl[sh + 1][c0] +
                  sl[sh + 1][c0 + 2];
      }
#pragma unroll
      for (int p = 0; p < 4; ++p) lnew[p] = DL * lnew[p] + linc[p];
    }
#pragma unroll
    for (int cil = 0; cil < 8; ++cil) {
#pragma unroll
      for (int kh = 0; kh < 3; ++kh) {
        // 6-wide window at slots cb+3..cb+8; row base 16B-aligned (stride 28)
        const float* rowp = &ysl[cil][sh + kh][0];
        float2 a2 = *(const float2*)(rowp + cb + 2);   // slots cb+2,cb+3
        float4 m4 = *(const float4*)(rowp + cb + 4);   // slots cb+4..cb+7
        float2 z2 = *(const float2*)(rowp + cb + 8);   // slots cb+8,cb+9
        const float yrow[6] = {a2.y, m4.x, m4.y, m4.z, m4.w, z2.x};
#pragma unroll
        for (int kw = 0; kw < 3; ++kw) {
          float4 wk = *(const float4*)&wsl[cil][3 * kh + kw][4 * g];
          const float wq[4] = {wk.x, wk.y, wk.z, wk.w};
#pragma unroll
          for (int q = 0; q < 4; ++q)
#pragma unroll
            for (int p = 0; p < 4; ++p)
              acc[q][p] = fmaf(wq[q], yrow[p + kw], acc[q][p]);
        }
      }
    }
  }

  // epilogue: f/e update (e-fold), out write, chansum partials
  const float4 bc4 = *(const float4*)&bias[4 * g];
  const float bc[4] = {bc4.x, bc4.y, bc4.z, bc4.w};
  float sp[4] = {0.f, 0.f, 0.f, 0.f};
#pragma unroll
  for (int q = 0; q < 4; ++q) {
    const int c = 4 * g + q;
    const size_t sidx = (size_t)b * CHW + (size_t)c * HW + (size_t)gh * W + gwc;
    const size_t oidx = (((size_t)b * T + t) * C + c) * (size_t)HW + (size_t)gh * W + gwc;
    float4 f4 = *(const float4*)(f + sidx);
    float4 e4 = *(const float4*)(e + sidx);
    float4 x4 = *(const float4*)(x + oidx);
    float fr[4] = {f4.x, f4.y, f4.z, f4.w};
    float er[4] = {e4.x, e4.y, e4.z, e4.w};
    float xr[4] = {x4.x, x4.y, x4.z, x4.w};
    float fo[4], eo[4], yn[4];
#pragma unroll
    for (int p = 0; p < 4; ++p) {
      float fn = DF * fr[p] + acc[q][p] + bc[q] + xr[p];
      float u = fmaf(0.5f * fn, lnew[p], fn);
      float yy = 1.f / (1.f + __expf(er[p] - u));
      fo[p] = fn;
      eo[p] = DE * er[p] + VE * yy;  // e_used(t+1)
      yn[p] = yy;
      sp[p] += yy;
    }
    *(float4*)(f + sidx) = make_float4(fo[0], fo[1], fo[2], fo[3]);
    *(float4*)(e + sidx) = make_float4(eo[0], eo[1], eo[2], eo[3]);
    *(float4*)(out + oidx) = make_float4(yn[0], yn[1], yn[2], yn[3]);
  }
  *(float4*)&sred[g][s][0] = make_float4(sp[0], sp[1], sp[2], sp[3]);
  __syncthreads();
  if (tid < 32) {  // g==0: (gh,gwc) spans the whole tile
    float4 a = *(const float4*)&sred[0][tid][0];
#pragma unroll
    for (int gg = 1; gg < 8; ++gg) {
      float4 bq = *(const float4*)&sred[gg][tid][0];
      a.x += bq.x; a.y += bq.y; a.z += bq.z; a.w += bq.w;
    }
    const size_t pidx = (size_t)b * HW + (size_t)gh * W + gwc;
    *(float4*)(s_out + pidx) = a;
    *(float4*)(lpl + pidx) = make_float4(lnew[0], lnew[1], lnew[2], lnew[3]);
  }
}

}  // namespace

extern "C" void kernel_launch(void* const* d_in, const int* in_sizes, int n_in,
                              void* d_out, int out_size, void* d_ws, size_t ws_size,
                              hipStream_t stream) {
  (void)in_sizes; (void)n_in; (void)out_size; (void)ws_size;
  const float* x = (const float*)d_in[0];     // (B,T,C,H,W)
  const float* wgt = (const float*)d_in[1];   // (C,C,3,3)
  const float* bias = (const float*)d_in[2];  // (C,)
  float* out = (float*)d_out;                 // (B,T,C,H,W)

  float* ws = (float*)d_ws;
  float* f = ws;                    // NSTATE
  float* e = f + NSTATE;            // NSTATE
  float* lpl = e + NSTATE;          // BHW (l is channel-uniform)
  float* sA = lpl + BHW;            // BHW
  float* sB = sA + BHW;             // BHW
  float* wtr = sB + BHW;            // 9216

  k_wtr<<<36, 256, 0, stream>>>(wgt, wtr);
  k_step0<<<1024, 256, 0, stream>>>(x, bias, f, e, lpl, out, sA);

  float* s_in = sA;
  float* s_out = sB;
  for (int t = 1; t < T; ++t) {
    k_step<<<1024, 256, 0, stream>>>(x, wtr, bias, s_in, s_out, f, e, lpl, out, t);
    float* tmp = s_in; s_in = s_out; s_out = tmp;
  }
}